// Round 4
// baseline (169.059 us; speedup 1.0000x reference)
//
#include <hip/hip_runtime.h>

// QuadraticConv2D: B=8 H=56 W=56 C=64 O=128, 55 quadratic pairs over (ones + 9 shifts)
// GEMM M=25088 pixels, K=55x64, N=128.
// R4: fp16 everywhere on the A/B path. No Q tile, no K-loop barriers: each wave
//     loads the 9 shift vectors per (mt,ks) slice into registers (9 ds_read_b128,
//     amortized over all 55 pairs) and forms A-frags with v_pk_mul_f16 in-register,
//     feeding mfma_f32_16x16x32_f16. B (weights) pre-cast to fp16, L2-resident.

#define CB 8
#define CH 56
#define CW 56
#define CC 64
#define CO 128
#define NPAIR 55
#define RS 72   // row stride in f16 (144 B): phase-wise conflict-free for all patterns

typedef __attribute__((ext_vector_type(8))) _Float16 v8hf;  // MFMA A/B frag (4 VGPRs)
typedef __attribute__((ext_vector_type(4))) float f4_t;     // MFMA accumulator frag

// ---- prep: kernel [55][64][128] f32 -> Bt [55][128][64] f16 (n-major, k contiguous)
__global__ __launch_bounds__(256) void prep_kernel(const float* __restrict__ K,
                                                   _Float16* __restrict__ Bt) {
  __shared__ float tile[CC * CO];
  const int p = blockIdx.x;
  const int t = threadIdx.x;
  const float* src = K + (size_t)p * CC * CO;
#pragma unroll
  for (int e = 0; e < 8; ++e) {
    const int idx = t * 4 + e * 1024;
    *(float4*)&tile[idx] = *(const float4*)&src[idx];
  }
  __syncthreads();
  const int n = t & 127;
  const int kh = t >> 7;
  _Float16 ov[32];
#pragma unroll
  for (int k = 0; k < 32; ++k)
    ov[k] = (_Float16)tile[(kh * 32 + k) * CO + n];
  _Float16* dst = Bt + ((size_t)p * CO + n) * CC + kh * 32;
#pragma unroll
  for (int g = 0; g < 4; ++g)
    *(v8hf*)(dst + g * 8) = *(const v8hf*)&ov[g * 8];
}

// ---- main: one block per (b,h) row. 256 threads = 4 waves, wave = N-quarter.
__global__ __launch_bounds__(256, 2) void quad_kernel(const float* __restrict__ in,
                                                      const _Float16* __restrict__ Bt,
                                                      float* __restrict__ out) {
  __shared__ _Float16 rowsH[3][64][RS];  // 3 input rows (f16), col = w+1 halo, 27.6 KB

  const int t = threadIdx.x;
  const int b = blockIdx.x / CH;
  const int h = blockIdx.x % CH;

  // stage 3 input rows into LDS (f16) with zero halo (w=-1, w>=56) / zero OOB rows
  {
    const int col = t >> 2;          // 0..63
    const int cg = (t & 3) * 16;     // 16-channel group
    const int w = col - 1;
#pragma unroll
    for (int r = 0; r < 3; ++r) {
      const int hh = h + r - 1;
      const bool valid = (hh >= 0) && (hh < CH) && (w >= 0) && (w < CW);
      float4 v0 = make_float4(0.f, 0.f, 0.f, 0.f), v1 = v0, v2 = v0, v3 = v0;
      if (valid) {
        const float* s = in + (((size_t)(b * CH + hh)) * CW + w) * CC + cg;
        v0 = *(const float4*)(s);
        v1 = *(const float4*)(s + 4);
        v2 = *(const float4*)(s + 8);
        v3 = *(const float4*)(s + 12);
      }
      _Float16 pv[16];
      pv[0] = (_Float16)v0.x;  pv[1] = (_Float16)v0.y;  pv[2] = (_Float16)v0.z;  pv[3] = (_Float16)v0.w;
      pv[4] = (_Float16)v1.x;  pv[5] = (_Float16)v1.y;  pv[6] = (_Float16)v1.z;  pv[7] = (_Float16)v1.w;
      pv[8] = (_Float16)v2.x;  pv[9] = (_Float16)v2.y;  pv[10] = (_Float16)v2.z; pv[11] = (_Float16)v2.w;
      pv[12] = (_Float16)v3.x; pv[13] = (_Float16)v3.y; pv[14] = (_Float16)v3.z; pv[15] = (_Float16)v3.w;
      _Float16* d = &rowsH[r][col][cg];
      *(v8hf*)(d) = *(const v8hf*)&pv[0];
      *(v8hf*)(d + 8) = *(const v8hf*)&pv[8];
    }
  }

  const int lane = t & 63;
  const int wid = t >> 6;     // N-quarter 0..3
  const int nl = lane & 15;
  const int qd = lane >> 4;

  f4_t acc[4][2];
#pragma unroll
  for (int mt = 0; mt < 4; ++mt)
#pragma unroll
    for (int nt = 0; nt < 2; ++nt)
      acc[mt][nt] = (f4_t){0.f, 0.f, 0.f, 0.f};

  __syncthreads();  // rowsH ready; no further barriers

  // B-frag base: Bt[p][n][k], n = wid*32 + nt*16 + nl, k = ks*32 + qd*8
  const _Float16* Bl = Bt + ((size_t)(wid * 32 + nl)) * CC + qd * 8;
  const v8hf vone = {1, 1, 1, 1, 1, 1, 1, 1};

#pragma unroll 1
  for (int g = 0; g < 2; ++g) {  // M-halves: mt = g*2 + mtL
    // per-(mtL,term) LDS base pointers (ks folded in as +32 offset later)
    const _Float16* sp0[9];
    const _Float16* sp1[9];
#pragma unroll
    for (int tt = 0; tt < 9; ++tt) {
      const int rr = tt / 3, sc = tt % 3;
      int c0 = g * 32 + nl + sc;           // mtL=0: m = g*32 + nl
      int c1 = c0 + 16;                     // mtL=1
      c0 = c0 > 63 ? 63 : c0;               // pad-m rows: clamp (values masked at write)
      c1 = c1 > 63 ? 63 : c1;
      sp0[tt] = &rowsH[rr][c0][qd * 8];
      sp1[tt] = &rowsH[rr][c1][qd * 8];
    }
#pragma unroll 1
    for (int ks = 0; ks < 2; ++ks) {
      v8hf s0[9], s1[9];
#pragma unroll
      for (int tt = 0; tt < 9; ++tt) {
        s0[tt] = *(const v8hf*)(sp0[tt] + ks * 32);
        s1[tt] = *(const v8hf*)(sp1[tt] + ks * 32);
      }
      const _Float16* bp = Bl + ks * 32;

#define DO_PAIR(A0, A1)                                                                  \
      {                                                                                  \
        const v8hf b0 = *(const v8hf*)(bp);                                              \
        const v8hf b1 = *(const v8hf*)(bp + 16 * CC);                                    \
        acc[g * 2 + 0][0] = __builtin_amdgcn_mfma_f32_16x16x32_f16((A0), b0, acc[g * 2 + 0][0], 0, 0, 0); \
        acc[g * 2 + 0][1] = __builtin_amdgcn_mfma_f32_16x16x32_f16((A0), b1, acc[g * 2 + 0][1], 0, 0, 0); \
        acc[g * 2 + 1][0] = __builtin_amdgcn_mfma_f32_16x16x32_f16((A1), b0, acc[g * 2 + 1][0], 0, 0, 0); \
        acc[g * 2 + 1][1] = __builtin_amdgcn_mfma_f32_16x16x32_f16((A1), b1, acc[g * 2 + 1][1], 0, 0, 0); \
        bp += (size_t)CO * CC;                                                           \
      }

      // pair 0: (ones, ones)
      DO_PAIR(vone, vone);
      // pairs (0, j), j = 1..9: A = S_j directly (no mul)
#pragma unroll
      for (int j = 1; j <= 9; ++j)
        DO_PAIR(s0[j - 1], s1[j - 1]);
      // pairs (i, j), 1 <= i <= j <= 9: A = S_i * S_j (v_pk_mul_f16)
#pragma unroll
      for (int i = 1; i <= 9; ++i)
#pragma unroll
        for (int j = i; j <= 9; ++j) {
          const v8hf a0 = s0[i - 1] * s0[j - 1];
          const v8hf a1 = s1[i - 1] * s1[j - 1];
          DO_PAIR(a0, a1);
        }
#undef DO_PAIR
    }
  }

  // epilogue: C/D layout col=lane&15 (n), row=(lane>>4)*4+reg (m)
  float* obase = out + ((size_t)(b * CH + h) * CW) * CO + wid * 32;
#pragma unroll
  for (int mt = 0; mt < 4; ++mt)
#pragma unroll
    for (int r4 = 0; r4 < 4; ++r4) {
      const int wp = mt * 16 + qd * 4 + r4;
      if (wp < CW) {
#pragma unroll
        for (int nt = 0; nt < 2; ++nt)
          obase[(size_t)wp * CO + nt * 16 + nl] = acc[mt][nt][r4];
      }
    }
}

extern "C" void kernel_launch(void* const* d_in, const int* in_sizes, int n_in,
                              void* d_out, int out_size, void* d_ws, size_t ws_size,
                              hipStream_t stream) {
  const float* in = (const float*)d_in[0];      // [8,56,56,64] f32
  const float* K = (const float*)d_in[1];       // [55,64,128] f32
  float* out = (float*)d_out;                   // [8,56,56,128] f32
  _Float16* Bt = (_Float16*)d_ws;               // [55][128][64] f16 = 901,120 B
  (void)in_sizes; (void)n_in; (void)out_size; (void)ws_size;

  prep_kernel<<<NPAIR, 256, 0, stream>>>(K, Bt);
  quad_kernel<<<CB * CH, 256, 0, stream>>>(in, Bt, out);
}

// Round 5
// 120.207 us; speedup vs baseline: 1.4064x; 1.4064x over previous
//
#include <hip/hip_runtime.h>

// QuadraticConv2D: B=8 H=56 W=56 C=64 O=128, 55 quadratic pairs over (ones + 9 shifts)
// GEMM M=25088 pixels, K=55x64, N=128.
// R5: barrier-free K-loop, A-frags formed in-register with v_pk_mul_f16 from 9 shift
//     vectors held in VGPRs (NO pointer arrays -> no scratch; R4's spill bug fixed),
//     mfma_f32_32x32x16_f16 (2 m-tiles/wave, 72 VGPRs of shift state vs 144).
//     B (weights) pre-cast fp16, n-major k-contig, loaded once per (pair,ks) per wave.

#define CB 8
#define CH 56
#define CW 56
#define CC 64
#define CO 128
#define NPAIR 55
#define RS 72   // row stride in f16 (144 B): 8-lane b128 phases cover all 32 banks

typedef __attribute__((ext_vector_type(8))) _Float16 v8hf;  // MFMA A/B frag (4 VGPRs)
typedef __attribute__((ext_vector_type(16))) float f16f;    // 32x32 accumulator (16 VGPRs)

// ---- prep: kernel [55][64][128] f32 -> Bt [55][128][64] f16 (n-major, k contiguous)
__global__ __launch_bounds__(256) void prep_kernel(const float* __restrict__ K,
                                                   _Float16* __restrict__ Bt) {
  __shared__ float tile[CC * CO];
  const int p = blockIdx.x;
  const int t = threadIdx.x;
  const float* src = K + (size_t)p * CC * CO;
#pragma unroll
  for (int e = 0; e < 8; ++e) {
    const int idx = t * 4 + e * 1024;
    *(float4*)&tile[idx] = *(const float4*)&src[idx];
  }
  __syncthreads();
  const int n = t & 127;
  const int kh = t >> 7;
  _Float16 ov[32];
#pragma unroll
  for (int k = 0; k < 32; ++k)
    ov[k] = (_Float16)tile[(kh * 32 + k) * CO + n];
  _Float16* dst = Bt + ((size_t)p * CO + n) * CC + kh * 32;
#pragma unroll
  for (int g = 0; g < 4; ++g)
    *(v8hf*)(dst + g * 8) = *(const v8hf*)&ov[g * 8];
}

// ---- main: one block per (b,h) row. 256 threads = 4 waves, wave = N-quarter.
__global__ __launch_bounds__(256, 2) void quad_kernel(const float* __restrict__ in,
                                                      const _Float16* __restrict__ Bt,
                                                      float* __restrict__ out) {
  __shared__ _Float16 rowsH[3][64][RS];  // 3 input rows (f16), col = w+1 halo, 27.6 KB

  const int t = threadIdx.x;
  const int b = blockIdx.x / CH;
  const int hrow = blockIdx.x % CH;

  // stage 3 input rows into LDS (f16) with zero halo (w=-1, w>=56) / zero OOB rows
  {
    const int col = t >> 2;          // 0..63
    const int cg = (t & 3) * 16;     // 16-channel group
    const int w = col - 1;
#pragma unroll
    for (int r = 0; r < 3; ++r) {
      const int hh = hrow + r - 1;
      const bool valid = (hh >= 0) && (hh < CH) && (w >= 0) && (w < CW);
      float4 v0 = make_float4(0.f, 0.f, 0.f, 0.f), v1 = v0, v2 = v0, v3 = v0;
      if (valid) {
        const float* s = in + (((size_t)(b * CH + hh)) * CW + w) * CC + cg;
        v0 = *(const float4*)(s);
        v1 = *(const float4*)(s + 4);
        v2 = *(const float4*)(s + 8);
        v3 = *(const float4*)(s + 12);
      }
      _Float16 pv[16];
      pv[0] = (_Float16)v0.x;  pv[1] = (_Float16)v0.y;  pv[2] = (_Float16)v0.z;  pv[3] = (_Float16)v0.w;
      pv[4] = (_Float16)v1.x;  pv[5] = (_Float16)v1.y;  pv[6] = (_Float16)v1.z;  pv[7] = (_Float16)v1.w;
      pv[8] = (_Float16)v2.x;  pv[9] = (_Float16)v2.y;  pv[10] = (_Float16)v2.z; pv[11] = (_Float16)v2.w;
      pv[12] = (_Float16)v3.x; pv[13] = (_Float16)v3.y; pv[14] = (_Float16)v3.z; pv[15] = (_Float16)v3.w;
      _Float16* d = &rowsH[r][col][cg];
      *(v8hf*)(d) = *(const v8hf*)&pv[0];
      *(v8hf*)(d + 8) = *(const v8hf*)&pv[8];
    }
  }

  const int lane = t & 63;
  const int nq = t >> 6;        // N-quarter 0..3
  const int ml = lane & 31;     // 32x32 MFMA: m (A) / n (B) lane index
  const int hk = lane >> 5;     // k-half selector
  const int h8 = hk * 8;

  f16f acc0, acc1;
#pragma unroll
  for (int r = 0; r < 16; ++r) { acc0[r] = 0.f; acc1[r] = 0.f; }

  __syncthreads();  // rowsH ready; no further barriers

  // B-frag lane base: Bt[p][n][k], n = nq*32 + ml, k = ks*16 + h8
  const _Float16* Bn = Bt + ((size_t)(nq * 32 + ml)) * CC + h8;
  const v8hf vone = {1, 1, 1, 1, 1, 1, 1, 1};

#pragma unroll 1
  for (int ks = 0; ks < 4; ++ks) {  // K=64 channels in 4 steps of 16
    const int koff = ks * 16 + h8;
    // load the 9 shift vectors for both m-tiles into registers (value arrays,
    // constant-indexed after unroll -> full SROA, no scratch)
    v8hf sA[9], sB[9];
#pragma unroll
    for (int tt = 0; tt < 9; ++tt) {
      const int rr = tt / 3, sc = tt % 3;
      sA[tt] = *(const v8hf*)&rowsH[rr][ml + sc][koff];          // m = ml (0..31), +sc <= 33
      int cb = 32 + ml + sc; cb = cb > 63 ? 63 : cb;             // m-tile 1, clamp (cols>=58 are zero)
      sB[tt] = *(const v8hf*)&rowsH[rr][cb][koff];
    }
    const _Float16* bks = Bn + ks * 16;
    int p = 0;
#define DOP(AV0, AV1)                                                                    \
    {                                                                                    \
      const v8hf bb = *(const v8hf*)(bks + (size_t)p * (CO * CC));                       \
      acc0 = __builtin_amdgcn_mfma_f32_32x32x16_f16((AV0), bb, acc0, 0, 0, 0);           \
      acc1 = __builtin_amdgcn_mfma_f32_32x32x16_f16((AV1), bb, acc1, 0, 0, 0);           \
      ++p;                                                                               \
    }
    // pair (0,0): ones
    DOP(vone, vone);
    // pairs (0,j): A = S_j directly
#pragma unroll
    for (int j = 1; j <= 9; ++j)
      DOP(sA[j - 1], sB[j - 1]);
    // pairs (i,j), 1<=i<=j<=9: A = S_i*S_j (v_pk_mul_f16 x4)
#pragma unroll
    for (int i = 1; i <= 9; ++i)
#pragma unroll
      for (int j = i; j <= 9; ++j) {
        const v8hf a0 = sA[i - 1] * sA[j - 1];
        const v8hf a1 = sB[i - 1] * sB[j - 1];
        DOP(a0, a1);
      }
#undef DOP
  }

  // epilogue: 32x32 C/D layout col=lane&31 (n), row=(reg&3)+8*(reg>>2)+4*(lane>>5) (m)
  float* ob = out + ((size_t)(b * CH + hrow) * CW) * CO + nq * 32 + ml;
#pragma unroll
  for (int r = 0; r < 16; ++r) {  // m-tile 0: rows 0..31, all real
    const int wp = (r & 3) + 8 * (r >> 2) + 4 * hk;
    ob[(size_t)wp * CO] = acc0[r];
  }
#pragma unroll
  for (int r = 0; r < 12; ++r) {  // m-tile 1: regs 12..15 are rows 56..63 (pad), skip
    const int wp = 32 + (r & 3) + 8 * (r >> 2) + 4 * hk;
    ob[(size_t)wp * CO] = acc1[r];
  }
}

extern "C" void kernel_launch(void* const* d_in, const int* in_sizes, int n_in,
                              void* d_out, int out_size, void* d_ws, size_t ws_size,
                              hipStream_t stream) {
  const float* in = (const float*)d_in[0];      // [8,56,56,64] f32
  const float* K = (const float*)d_in[1];       // [55,64,128] f32
  float* out = (float*)d_out;                   // [8,56,56,128] f32
  _Float16* Bt = (_Float16*)d_ws;               // [55][128][64] f16 = 901,120 B
  (void)in_sizes; (void)n_in; (void)out_size; (void)ws_size;

  prep_kernel<<<NPAIR, 256, 0, stream>>>(K, Bt);
  quad_kernel<<<CB * CH, 256, 0, stream>>>(in, Bt, out);
}

// Round 6
// 97.656 us; speedup vs baseline: 1.7312x; 1.2309x over previous
//
#include <hip/hip_runtime.h>

// QuadraticConv2D: B=8 H=56 W=56 C=64 O=128, 55 quadratic pairs over (ones + 9 shifts)
// GEMM M=25088 pixels, K=55x64, N=128.
// R6: 2 rows/block (224 blocks, 1/CU, balanced), 4 waves (wave = N-quarter), each wave
//     4 m-tiles (B reuse x4 -> per-CU B-VMEM ~900 KB, floor ~6.7 us). Barrier-free
//     K-loop; A-frags in-register via v_pk_mul_f16; explicit B prefetch ring depth 11
//     (constant-indexed, 55%11==0) keeps ~11 b128 loads in flight per wave.

#define CB 8
#define CH 56
#define CW 56
#define CC 64
#define CO 128
#define RS 72   // row stride in f16 (144 B)

typedef __attribute__((ext_vector_type(8))) _Float16 v8hf;  // MFMA A/B frag (4 VGPRs)
typedef __attribute__((ext_vector_type(16))) float f16f;    // 32x32 accumulator

// pair tables: p-th pair (i,j), i=0..9, j=i..9 (reference order)
__device__ constexpr int PII[55] = {0,0,0,0,0,0,0,0,0,0, 1,1,1,1,1,1,1,1,1, 2,2,2,2,2,2,2,2,
                                    3,3,3,3,3,3,3, 4,4,4,4,4,4, 5,5,5,5,5, 6,6,6,6, 7,7,7, 8,8, 9};
__device__ constexpr int PJJ[55] = {0,1,2,3,4,5,6,7,8,9, 1,2,3,4,5,6,7,8,9, 2,3,4,5,6,7,8,9,
                                    3,4,5,6,7,8,9, 4,5,6,7,8,9, 5,6,7,8,9, 6,7,8,9, 7,8,9, 8,9, 9};

// ---- prep: kernel [55][64][128] f32 -> Bt [55][128][64] f16 (n-major, k contiguous)
__global__ __launch_bounds__(256) void prep_kernel(const float* __restrict__ K,
                                                   _Float16* __restrict__ Bt) {
  __shared__ float tile[CC * CO];
  const int p = blockIdx.x;
  const int t = threadIdx.x;
  const float* src = K + (size_t)p * CC * CO;
#pragma unroll
  for (int e = 0; e < 8; ++e) {
    const int idx = t * 4 + e * 1024;
    *(float4*)&tile[idx] = *(const float4*)&src[idx];
  }
  __syncthreads();
  const int n = t & 127;
  const int kh = t >> 7;
  _Float16 ov[32];
#pragma unroll
  for (int k = 0; k < 32; ++k)
    ov[k] = (_Float16)tile[(kh * 32 + k) * CO + n];
  _Float16* dst = Bt + ((size_t)p * CO + n) * CC + kh * 32;
#pragma unroll
  for (int g = 0; g < 4; ++g)
    *(v8hf*)(dst + g * 8) = *(const v8hf*)&ov[g * 8];
}

// ---- main: one block per (b, row-pair). 256 threads = 4 waves, wave = N-quarter.
// Wave computes 4 m-tiles: (row h0+rt, cols ct*32..+32) for rt,ct in {0,1}x{0,1}.
__global__ __launch_bounds__(256, 1) void quad_kernel(const float* __restrict__ in,
                                                      const _Float16* __restrict__ Bt,
                                                      float* __restrict__ out) {
  __shared__ _Float16 rowsH[4][64][RS];  // rows h0-1..h0+2 (f16), col = w+1 halo, 36.9 KB

  const int t = threadIdx.x;
  const int b = blockIdx.x / (CH / 2);
  const int h0 = (blockIdx.x % (CH / 2)) * 2;

  // stage 4 input rows into LDS (f16) with zero halo (w=-1, w>=56) / zero OOB rows
  {
    const int col = t >> 2;          // 0..63
    const int cg = (t & 3) * 16;     // 16-channel group
    const int w = col - 1;
#pragma unroll
    for (int r = 0; r < 4; ++r) {
      const int hh = h0 + r - 1;
      const bool valid = (hh >= 0) && (hh < CH) && (w >= 0) && (w < CW);
      float4 v0 = make_float4(0.f, 0.f, 0.f, 0.f), v1 = v0, v2 = v0, v3 = v0;
      if (valid) {
        const float* s = in + (((size_t)(b * CH + hh)) * CW + w) * CC + cg;
        v0 = *(const float4*)(s);
        v1 = *(const float4*)(s + 4);
        v2 = *(const float4*)(s + 8);
        v3 = *(const float4*)(s + 12);
      }
      _Float16 pv[16];
      pv[0] = (_Float16)v0.x;  pv[1] = (_Float16)v0.y;  pv[2] = (_Float16)v0.z;  pv[3] = (_Float16)v0.w;
      pv[4] = (_Float16)v1.x;  pv[5] = (_Float16)v1.y;  pv[6] = (_Float16)v1.z;  pv[7] = (_Float16)v1.w;
      pv[8] = (_Float16)v2.x;  pv[9] = (_Float16)v2.y;  pv[10] = (_Float16)v2.z; pv[11] = (_Float16)v2.w;
      pv[12] = (_Float16)v3.x; pv[13] = (_Float16)v3.y; pv[14] = (_Float16)v3.z; pv[15] = (_Float16)v3.w;
      _Float16* d = &rowsH[r][col][cg];
      *(v8hf*)(d) = *(const v8hf*)&pv[0];
      *(v8hf*)(d + 8) = *(const v8hf*)&pv[8];
    }
  }

  const int lane = t & 63;
  const int nq = t >> 6;        // N-quarter 0..3
  const int ml = lane & 31;     // 32x32 MFMA: m (A) / n (B) lane index
  const int hk = lane >> 5;     // k-half selector
  const int h8 = hk * 8;

  f16f acc0, acc1, acc2, acc3;
#pragma unroll
  for (int r = 0; r < 16; ++r) { acc0[r] = 0.f; acc1[r] = 0.f; acc2[r] = 0.f; acc3[r] = 0.f; }

  // B-frag lane base: Bt[p][n][k], n = nq*32 + ml, k = ks*16 + h8
  const _Float16* Bn = Bt + ((size_t)(nq * 32 + ml)) * CC + h8;
  const v8hf vone = {1, 1, 1, 1, 1, 1, 1, 1};

  // prefetch ring: steps 0..10 (ks=0, pairs 0..10)
  v8hf ring[11];
#pragma unroll
  for (int p = 0; p < 11; ++p)
    ring[p] = *(const v8hf*)(Bn + (size_t)p * (CO * CC));

  __syncthreads();  // rowsH ready; no further barriers

#pragma unroll 1
  for (int ks = 0; ks < 4; ++ks) {  // K=64 channels in 4 steps of 16
    const int koff = ks * 16 + h8;
    // shift vectors for the 4 m-tiles (value arrays, constant-indexed -> registers)
    v8hf s0[9], s1[9], s2[9], s3[9];
#pragma unroll
    for (int tt = 0; tt < 9; ++tt) {
      const int rr = tt / 3, sc = tt % 3;
      const int c0 = ml + sc;                      // tile col 0: max 33, in range
      int c1 = 32 + ml + sc; c1 = c1 > 63 ? 63 : c1;  // tile col 1: clamp (cols>=58 staged zero)
      s0[tt] = *(const v8hf*)&rowsH[rr][c0][koff];
      s1[tt] = *(const v8hf*)&rowsH[rr][c1][koff];
      s2[tt] = *(const v8hf*)&rowsH[rr + 1][c0][koff];
      s3[tt] = *(const v8hf*)&rowsH[rr + 1][c1][koff];
    }
    const int ksn = (ks < 3) ? ks + 1 : 3;  // tail prefetch clamps (redundant, harmless)
#pragma unroll
    for (int p = 0; p < 55; ++p) {
      const v8hf bb = ring[p % 11];
      // prefetch global step s+11 into the slot just consumed
      {
        const int p2 = (p < 44) ? p + 11 : p - 44;   // p constant after unroll -> folds
        const _Float16* ba = Bn + (size_t)p2 * (CO * CC) + ((p < 44) ? ks : ksn) * 16;
        ring[p % 11] = *(const v8hf*)ba;
      }
      const int pi = PII[p], pj = PJJ[p];
      v8hf a0, a1, a2, a3;
      if (pi == 0) {
        if (pj == 0) { a0 = vone; a1 = vone; a2 = vone; a3 = vone; }
        else { a0 = s0[pj - 1]; a1 = s1[pj - 1]; a2 = s2[pj - 1]; a3 = s3[pj - 1]; }
      } else {
        a0 = s0[pi - 1] * s0[pj - 1];
        a1 = s1[pi - 1] * s1[pj - 1];
        a2 = s2[pi - 1] * s2[pj - 1];
        a3 = s3[pi - 1] * s3[pj - 1];
      }
      acc0 = __builtin_amdgcn_mfma_f32_32x32x16_f16(a0, bb, acc0, 0, 0, 0);
      acc1 = __builtin_amdgcn_mfma_f32_32x32x16_f16(a1, bb, acc1, 0, 0, 0);
      acc2 = __builtin_amdgcn_mfma_f32_32x32x16_f16(a2, bb, acc2, 0, 0, 0);
      acc3 = __builtin_amdgcn_mfma_f32_32x32x16_f16(a3, bb, acc3, 0, 0, 0);
    }
  }

  // epilogue: 32x32 C/D layout col=lane&31 (n), row=(reg&3)+8*(reg>>2)+4*(lane>>5) (m)
  const size_t rowstride = (size_t)CW * CO;
  float* ob0 = out + ((size_t)(b * CH + h0) * CW) * CO + nq * 32 + ml;
  float* ob1 = ob0 + rowstride;
#pragma unroll
  for (int r = 0; r < 16; ++r) {  // col-tile 0: w = 0..31, all real
    const int wp = (r & 3) + 8 * (r >> 2) + 4 * hk;
    ob0[(size_t)wp * CO] = acc0[r];
    ob1[(size_t)wp * CO] = acc2[r];
  }
#pragma unroll
  for (int r = 0; r < 12; ++r) {  // col-tile 1: w = 32..55; regs 12..15 are w>=56 pad
    const int wp = 32 + (r & 3) + 8 * (r >> 2) + 4 * hk;
    ob0[(size_t)wp * CO] = acc1[r];
    ob1[(size_t)wp * CO] = acc3[r];
  }
}

extern "C" void kernel_launch(void* const* d_in, const int* in_sizes, int n_in,
                              void* d_out, int out_size, void* d_ws, size_t ws_size,
                              hipStream_t stream) {
  const float* in = (const float*)d_in[0];      // [8,56,56,64] f32
  const float* K = (const float*)d_in[1];       // [55,64,128] f32
  float* out = (float*)d_out;                   // [8,56,56,128] f32
  _Float16* Bt = (_Float16*)d_ws;               // [55][128][64] f16 = 901,120 B
  (void)in_sizes; (void)n_in; (void)out_size; (void)ws_size;

  prep_kernel<<<55, 256, 0, stream>>>(K, Bt);
  quad_kernel<<<CB * (CH / 2), 256, 0, stream>>>(in, Bt, out);
}